// Round 1
// baseline (1185.787 us; speedup 1.0000x reference)
//
#include <hip/hip_runtime.h>
#include <hip/hip_bf16.h>
#include <stdint.h>

// ---------------- constants ----------------
#define DIMC 512
#define HEADS 16
#define HEAD_DIM 32
#define NTOK 49            // tokens per window (7x7)
#define SCALE 0.17677669529663687f   // 1/sqrt(32)

typedef unsigned short u16;
typedef short bf16x8 __attribute__((ext_vector_type(8)));
typedef float f32x4 __attribute__((ext_vector_type(4)));
typedef u16 u16x4 __attribute__((ext_vector_type(4)));

#define MFMA16(a, b, c) __builtin_amdgcn_mfma_f32_16x16x32_bf16((a), (b), (c), 0, 0, 0)

__device__ __forceinline__ u16 f2bf(float f) {
  __hip_bfloat16 h = __float2bfloat16(f);   // RNE
  u16 u;
  __builtin_memcpy(&u, &h, 2);
  return u;
}

// async global->LDS, 16 bytes per lane (wave-uniform LDS base + lane*16)
__device__ __forceinline__ void gld16(const void* g, void* l) {
  __builtin_amdgcn_global_load_lds(
      (const __attribute__((address_space(1))) uint32_t*)g,
      (__attribute__((address_space(3))) uint32_t*)l, 16, 0, 0);
}

// ---------------- fp32 -> bf16 convert (weights) ----------------
__global__ void cvt_f32_bf16(const float* __restrict__ in, u16* __restrict__ out, int n) {
  int i = (blockIdx.x * 256 + threadIdx.x) * 4;
  if (i < n) {
    float4 v = *(const float4*)(in + i);
    u16x4 r;
    r.x = f2bf(v.x); r.y = f2bf(v.y); r.z = f2bf(v.z); r.w = f2bf(v.w);
    *(u16x4*)(out + i) = r;
  }
}

// ---------------- bias+mask precompute: [64][16][64][64] fp32, pad = -1e30 ----
__global__ void biasmask_kernel(const float* __restrict__ table, const float* __restrict__ mask,
                                float* __restrict__ bm) {
  const int wm = blockIdx.x >> 4;   // 0..63  (window-in-image)
  const int h  = blockIdx.x & 15;   // 0..15
  for (int e = threadIdx.x; e < 4096; e += 256) {
    const int i = e >> 6, j = e & 63;
    float v;
    if (i < NTOK && j < NTOK) {
      const int yi = i / 7, xi = i % 7, yj = j / 7, xj = j % 7;
      const int idx = (yi - yj + 6) * 13 + (xi - xj + 6);
      v = table[idx * HEADS + h] + mask[wm * (NTOK * NTOK) + i * NTOK + j];
    } else {
      v = -1e30f;   // kill padded keys in softmax; padded queries harmless
    }
    bm[(size_t)blockIdx.x * 4096 + e] = v;
  }
}

// ---------------- GEMM: C[M,N] = A[M,K] @ B[N,K]^T + bias ----------------
// A: fp32 (reg-staged+converted) or bf16 (global_load_lds). B: bf16 N x K.
// 128x128 tile, BK=32, 4 waves (2x2 of 64x64), mfma 16x16x32 bf16.
template<bool A_F32, bool OUT_BF16, bool QKV_SCALE>
__global__ void gemm_tn(const void* __restrict__ Ap, const u16* __restrict__ Bp,
                        const float* __restrict__ bias, void* __restrict__ Cp,
                        int M, int N, int K) {
  constexpr int ASTR = A_F32 ? 40 : 32;  // pad reg-staged A to dodge bank conflicts
  __shared__ u16 As[128 * ASTR];
  __shared__ u16 Bs[128 * 32];
  const int t = threadIdx.x;
  const int lane = t & 63;
  const int wv = t >> 6, wr = wv >> 1, wc = wv & 1;
  const int lr = lane & 15, lg = lane >> 4;
  const int bn0 = blockIdx.x * 128;
  const int bm0 = blockIdx.y * 128;

  f32x4 acc[4][4] = {};

  const int c0 = t, c1 = t + 256;   // 16B chunk ids for gld16 staging
  const int nK = K >> 5;

  for (int kt = 0; kt < nK; ++kt) {
    const int k0 = kt << 5;
    __syncthreads();  // previous compute done; LDS safe to overwrite
    // stage B (128 rows x 32 cols bf16 = 8KB) via async copy
    gld16(Bp + (size_t)(bn0 + (c0 >> 2)) * K + k0 + (c0 & 3) * 8, Bs + c0 * 8);
    gld16(Bp + (size_t)(bn0 + (c1 >> 2)) * K + k0 + (c1 & 3) * 8, Bs + c1 * 8);
    if (A_F32) {
      // each thread: 16 fp32 (64B) -> 16 bf16 (32B LDS)
      const float* A = (const float*)Ap;
      const float* src = A + (size_t)(bm0 + (t >> 1)) * K + k0 + (t & 1) * 16;
      float4 v0 = ((const float4*)src)[0];
      float4 v1 = ((const float4*)src)[1];
      float4 v2 = ((const float4*)src)[2];
      float4 v3 = ((const float4*)src)[3];
      bf16x8 p0, p1;
      p0[0] = f2bf(v0.x); p0[1] = f2bf(v0.y); p0[2] = f2bf(v0.z); p0[3] = f2bf(v0.w);
      p0[4] = f2bf(v1.x); p0[5] = f2bf(v1.y); p0[6] = f2bf(v1.z); p0[7] = f2bf(v1.w);
      p1[0] = f2bf(v2.x); p1[1] = f2bf(v2.y); p1[2] = f2bf(v2.z); p1[3] = f2bf(v2.w);
      p1[4] = f2bf(v3.x); p1[5] = f2bf(v3.y); p1[6] = f2bf(v3.z); p1[7] = f2bf(v3.w);
      u16* dst = &As[(t >> 1) * ASTR + (t & 1) * 16];
      *(bf16x8*)dst = p0;
      *(bf16x8*)(dst + 8) = p1;
    } else {
      const u16* A = (const u16*)Ap;
      gld16(A + (size_t)(bm0 + (c0 >> 2)) * K + k0 + (c0 & 3) * 8, As + c0 * 8);
      gld16(A + (size_t)(bm0 + (c1 >> 2)) * K + k0 + (c1 & 3) * 8, As + c1 * 8);
    }
    __syncthreads();  // drains vmcnt (gld16) + lgkm (A writes)

    bf16x8 af[4], bfr[4];
#pragma unroll
    for (int i = 0; i < 4; ++i)
      af[i] = *(const bf16x8*)&As[(wr * 64 + i * 16 + lr) * ASTR + lg * 8];
#pragma unroll
    for (int j = 0; j < 4; ++j)
      bfr[j] = *(const bf16x8*)&Bs[(wc * 64 + j * 16 + lr) * 32 + lg * 8];
#pragma unroll
    for (int i = 0; i < 4; ++i)
#pragma unroll
      for (int j = 0; j < 4; ++j)
        acc[i][j] = MFMA16(af[i], bfr[j], acc[i][j]);
  }

  // epilogue: D row = (lane>>4)*4 + r, col = lane&15 (m89-verified layout)
#pragma unroll
  for (int j = 0; j < 4; ++j) {
    const int col = bn0 + wc * 64 + j * 16 + lr;
    const float bv = bias[col];
    const float sc = (QKV_SCALE && col < DIMC) ? SCALE : 1.0f;
#pragma unroll
    for (int i = 0; i < 4; ++i) {
      const int row0 = bm0 + wr * 64 + i * 16 + lg * 4;
#pragma unroll
      for (int r = 0; r < 4; ++r) {
        const float val = (acc[i][j][r] + bv) * sc;
        if (OUT_BF16)
          ((u16*)Cp)[(size_t)(row0 + r) * N + col] = f2bf(val);
        else
          ((float*)Cp)[(size_t)(row0 + r) * N + col] = val;
      }
    }
  }
}

// ---------------- fused window attention ----------------
// 1 wave per (window, head). qkv: [B_*49][1536] bf16 (q scaled already).
// biasmask: [64*16][64*64] fp32 (pad -1e30). out: [B_*49][512] bf16.
__global__ void attn_win(const u16* __restrict__ qkv, const float* __restrict__ bmask,
                         u16* __restrict__ aout) {
  __shared__ u16 P[4][64 * 72];   // per-wave P tile, stride 72 (pad)
  const int t = threadIdx.x, lane = t & 63, wv = t >> 6;
  const int lr = lane & 15, lg = lane >> 4;
  const int w = blockIdx.x >> 2;
  const int h = ((blockIdx.x & 3) << 2) + wv;
  const size_t base = (size_t)w * NTOK * 1536 + h * HEAD_DIM;

  const bf16x8 zf = {};
  bf16x8 qf[4], kf[4];
#pragma unroll
  for (int i = 0; i < 4; ++i) {
    const int row = i * 16 + lr;
    const size_t roff = base + (size_t)row * 1536 + lg * 8;
    qf[i] = (row < NTOK) ? *(const bf16x8*)&qkv[roff] : zf;          // Q(row, d..)
    kf[i] = (row < NTOK) ? *(const bf16x8*)&qkv[roff + DIMC] : zf;   // K(row, d..)
  }

  const f32x4 zc = {};
  f32x4 s[4][4];
#pragma unroll
  for (int i = 0; i < 4; ++i)
#pragma unroll
    for (int j = 0; j < 4; ++j)
      s[i][j] = MFMA16(qf[i], kf[j], zc);   // S = (Q*scale) K^T

  const float* bmp = bmask + (((size_t)(w & 63) * HEADS + h) << 12);
#pragma unroll
  for (int i = 0; i < 4; ++i)
#pragma unroll
    for (int r = 0; r < 4; ++r) {
      const int ii = i * 16 + lg * 4 + r;
#pragma unroll
      for (int j = 0; j < 4; ++j)
        s[i][j][r] += bmp[ii * 64 + j * 16 + lr];
    }

  // softmax over each row: 4 in-lane values x 16 lanes (shfl_xor 1,2,4,8)
#pragma unroll
  for (int i = 0; i < 4; ++i)
#pragma unroll
    for (int r = 0; r < 4; ++r) {
      float m = fmaxf(fmaxf(s[i][0][r], s[i][1][r]), fmaxf(s[i][2][r], s[i][3][r]));
      m = fmaxf(m, __shfl_xor(m, 1));
      m = fmaxf(m, __shfl_xor(m, 2));
      m = fmaxf(m, __shfl_xor(m, 4));
      m = fmaxf(m, __shfl_xor(m, 8));
      float sum = 0.f;
#pragma unroll
      for (int j = 0; j < 4; ++j) {
        const float e = __expf(s[i][j][r] - m);
        s[i][j][r] = e;
        sum += e;
      }
      sum += __shfl_xor(sum, 1);
      sum += __shfl_xor(sum, 2);
      sum += __shfl_xor(sum, 4);
      sum += __shfl_xor(sum, 8);
      const float rinv = __builtin_amdgcn_rcpf(sum);
#pragma unroll
      for (int j = 0; j < 4; ++j) s[i][j][r] *= rinv;
    }

  // P -> LDS (bf16), C/D layout scatter
  u16* Pw = &P[wv][0];
#pragma unroll
  for (int i = 0; i < 4; ++i)
#pragma unroll
    for (int r = 0; r < 4; ++r) {
      const int ii = i * 16 + lg * 4 + r;
#pragma unroll
      for (int j = 0; j < 4; ++j)
        Pw[ii * 72 + j * 16 + lr] = f2bf(s[i][j][r]);
    }

  // PV: out[i][d] = sum_k P[i][k] V[k][d]; K=64 (2 steps), pad keys have P==0
  f32x4 o[4][2] = {};
#pragma unroll
  for (int ks = 0; ks < 2; ++ks) {
    bf16x8 vf[2];
#pragma unroll
    for (int dn = 0; dn < 2; ++dn) {
#pragma unroll
      for (int e = 0; e < 8; ++e) {
        int kk = ks * 32 + lg * 8 + e;
        kk = kk < NTOK ? kk : 0;   // P is exactly 0 for padded keys
        vf[dn][e] = (short)qkv[base + 2 * DIMC + (size_t)kk * 1536 + dn * 16 + lr];
      }
    }
#pragma unroll
    for (int i = 0; i < 4; ++i) {
      const bf16x8 pa = *(const bf16x8*)&Pw[(i * 16 + lr) * 72 + ks * 32 + lg * 8];
#pragma unroll
      for (int dn = 0; dn < 2; ++dn)
        o[i][dn] = MFMA16(pa, vf[dn], o[i][dn]);
    }
  }

  // store attention output -> [token][h*32+d] bf16
#pragma unroll
  for (int i = 0; i < 4; ++i)
#pragma unroll
    for (int r = 0; r < 4; ++r) {
      const int row = i * 16 + lg * 4 + r;
      if (row < NTOK) {
        const size_t ob = ((size_t)w * NTOK + row) * DIMC + h * HEAD_DIM;
#pragma unroll
        for (int dn = 0; dn < 2; ++dn)
          aout[ob + dn * 16 + lr] = f2bf(o[i][dn][r]);
      }
    }
}

// ---------------- launch ----------------
extern "C" void kernel_launch(void* const* d_in, const int* in_sizes, int n_in,
                              void* d_out, int out_size, void* d_ws, size_t ws_size,
                              hipStream_t stream) {
  const float* x      = (const float*)d_in[0];   // (4096,49,512)
  const float* mask   = (const float*)d_in[1];   // (64,49,49)
  const float* qkv_w  = (const float*)d_in[2];   // (1536,512)
  const float* qkv_b  = (const float*)d_in[3];   // (1536,)
  const float* table  = (const float*)d_in[4];   // (169,16)
  const float* proj_w = (const float*)d_in[5];   // (512,512)
  const float* proj_b = (const float*)d_in[6];   // (512,)
  float* out = (float*)d_out;

  const int M = 4096 * NTOK;   // 200704

  char* ws = (char*)d_ws;
  u16*   qkv_bf   = (u16*)ws;                         // 200704*1536*2 = 616,562,688
  u16*   wqkv_bf  = (u16*)(ws + 616562688ull);        // 1536*512*2    = 1,572,864
  u16*   wproj_bf = (u16*)(ws + 618135552ull);        // 512*512*2     = 524,288
  float* biasmask = (float*)(ws + 618659840ull);      // 1024*4096*4   = 16,777,216
  u16*   attn_bf  = (u16*)(ws + 635437056ull);        // 200704*512*2  = 205,520,896
  // total 840,957,952 bytes

  cvt_f32_bf16<<<768, 256, 0, stream>>>(qkv_w, wqkv_bf, 1536 * 512);
  cvt_f32_bf16<<<256, 256, 0, stream>>>(proj_w, wproj_bf, 512 * 512);
  biasmask_kernel<<<1024, 256, 0, stream>>>(table, mask, biasmask);

  dim3 g1(1536 / 128, M / 128);   // (12, 1568): x = n-tile so B-panel stays L2-hot
  gemm_tn<true, true, true><<<g1, 256, 0, stream>>>(x, wqkv_bf, qkv_b, qkv_bf, M, 1536, 512);

  attn_win<<<4096 * 4, 256, 0, stream>>>(qkv_bf, biasmask, attn_bf);

  dim3 g2(512 / 128, M / 128);    // (4, 1568)
  gemm_tn<false, false, false><<<g2, 256, 0, stream>>>(attn_bf, wproj_bf, proj_b, out, M, 512, 512);
}

// Round 2
// 1012.220 us; speedup vs baseline: 1.1715x; 1.1715x over previous
//
#include <hip/hip_runtime.h>
#include <hip/hip_bf16.h>
#include <stdint.h>

// ---------------- constants ----------------
#define DIMC 512
#define HEADS 16
#define HEAD_DIM 32
#define NTOK 49            // tokens per window (7x7)
#define SCALE 0.17677669529663687f   // 1/sqrt(32)

typedef unsigned short u16;
typedef short bf16x8 __attribute__((ext_vector_type(8)));
typedef float f32x4 __attribute__((ext_vector_type(4)));
typedef u16 u16x4 __attribute__((ext_vector_type(4)));
typedef u16 u16x8 __attribute__((ext_vector_type(8)));

#define MFMA16(a, b, c) __builtin_amdgcn_mfma_f32_16x16x32_bf16((a), (b), (c), 0, 0, 0)

__device__ __forceinline__ u16 f2bf(float f) {
  __hip_bfloat16 h = __float2bfloat16(f);   // RNE
  u16 u;
  __builtin_memcpy(&u, &h, 2);
  return u;
}

// async global->LDS, 16 bytes per lane (wave-uniform LDS base + lane*16)
__device__ __forceinline__ void gld16(const void* g, void* l) {
  __builtin_amdgcn_global_load_lds(
      (const __attribute__((address_space(1))) uint32_t*)g,
      (__attribute__((address_space(3))) uint32_t*)l, 16, 0, 0);
}

// ---------------- fp32 -> bf16 convert (grid-stride, 8 elems/thread/iter) ----
__global__ void cvt_f32_bf16(const float* __restrict__ in, u16* __restrict__ out, int n) {
  const int stride = gridDim.x * blockDim.x;
  for (int i = blockIdx.x * blockDim.x + threadIdx.x; i * 8 < n; i += stride) {
    const float4 v0 = ((const float4*)(in + i * 8))[0];
    const float4 v1 = ((const float4*)(in + i * 8))[1];
    u16x8 r;
    r[0] = f2bf(v0.x); r[1] = f2bf(v0.y); r[2] = f2bf(v0.z); r[3] = f2bf(v0.w);
    r[4] = f2bf(v1.x); r[5] = f2bf(v1.y); r[6] = f2bf(v1.z); r[7] = f2bf(v1.w);
    *(u16x8*)(out + i * 8) = r;
  }
}

// ---------------- bias+mask precompute: [64][16][64][64] fp32, pad = -1e30 ----
__global__ void biasmask_kernel(const float* __restrict__ table, const float* __restrict__ mask,
                                float* __restrict__ bm) {
  const int wm = blockIdx.x >> 4;   // 0..63  (window-in-image)
  const int h  = blockIdx.x & 15;   // 0..15
  for (int e = threadIdx.x; e < 4096; e += 256) {
    const int i = e >> 6, j = e & 63;
    float v;
    if (i < NTOK && j < NTOK) {
      const int yi = i / 7, xi = i % 7, yj = j / 7, xj = j % 7;
      const int idx = (yi - yj + 6) * 13 + (xi - xj + 6);
      v = table[idx * HEADS + h] + mask[wm * (NTOK * NTOK) + i * NTOK + j];
    } else {
      v = -1e30f;   // kill padded keys in softmax; padded queries harmless
    }
    bm[(size_t)blockIdx.x * 4096 + e] = v;
  }
}

// ---------------- GEMM: C[M,N] = A[M,K] @ B[N,K]^T + bias (all bf16 in) ------
// 128x128 tile, BK=64, 4 waves (2x2 of 64x64), mfma 16x16x32 bf16.
// LDS [128][64] linear for gld16; XOR chunk-swizzle (chunk ^= row&7) applied to
// BOTH the global source address and the ds_read address (rule #21) -> uniform
// 8-access/bank on ds_read_b128 (= b128 floor, no conflict penalty).
// blockIdx: 1D, XCD-chunked bijective swizzle (nwg % 8 == 0 for all our grids).
template<bool OUT_BF16, bool QKV_SCALE>
__global__ void gemm_bf16(const u16* __restrict__ Ap, const u16* __restrict__ Bp,
                          const float* __restrict__ bias, void* __restrict__ Cp,
                          int M, int N, int K, int nxt) {
  __shared__ u16 As[128 * 64];
  __shared__ u16 Bs[128 * 64];
  const int t = threadIdx.x;
  const int lane = t & 63;
  // XCD swizzle: physical lin -> logical l so each XCD walks n-fast (A reuse in L2)
  const int q = gridDim.x >> 3;
  const int lin = blockIdx.x;
  const int l = (lin & 7) * q + (lin >> 3);
  const int bm0 = (l / nxt) * 128;
  const int bn0 = (l % nxt) * 128;
  const int wv = t >> 6, wr = wv >> 1, wc = wv & 1;
  const int lr = lane & 15, lg = lane >> 4;

  f32x4 acc[4][4] = {};

  // staging geometry: 1024 16B-chunks per tile, 4 per thread (c = t + 256k)
  int soff[4];  // element offset within tile row-block: row*K-relative col
#pragma unroll
  for (int k = 0; k < 4; ++k) {
    const int c = t + 256 * k;
    const int row = c >> 3, sub = c & 7;
    soff[k] = ((sub ^ (row & 7)) * 8);  // swizzled source column (elements)
  }

  const int nK = K >> 6;
  for (int kt = 0; kt < nK; ++kt) {
    const int k0 = kt << 6;
    __syncthreads();  // previous compute done; LDS safe to overwrite
#pragma unroll
    for (int k = 0; k < 4; ++k) {
      const int c = t + 256 * k;
      const int row = c >> 3;
      gld16(Ap + (size_t)(bm0 + row) * K + k0 + soff[k], As + c * 8);
      gld16(Bp + (size_t)(bn0 + row) * K + k0 + soff[k], Bs + c * 8);
    }
    __syncthreads();  // drains vmcnt(0): tiles ready

#pragma unroll
    for (int kk = 0; kk < 2; ++kk) {
      bf16x8 af[4], bfr[4];
#pragma unroll
      for (int i = 0; i < 4; ++i) {
        const int row = wr * 64 + i * 16 + lr;
        af[i] = *(const bf16x8*)&As[row * 64 + ((kk * 4 + lg) ^ (row & 7)) * 8];
      }
#pragma unroll
      for (int j = 0; j < 4; ++j) {
        const int row = wc * 64 + j * 16 + lr;
        bfr[j] = *(const bf16x8*)&Bs[row * 64 + ((kk * 4 + lg) ^ (row & 7)) * 8];
      }
#pragma unroll
      for (int i = 0; i < 4; ++i)
#pragma unroll
        for (int j = 0; j < 4; ++j)
          acc[i][j] = MFMA16(af[i], bfr[j], acc[i][j]);
    }
  }

  // epilogue: D row = (lane>>4)*4 + r, col = lane&15 (m89-verified layout)
#pragma unroll
  for (int j = 0; j < 4; ++j) {
    const int col = bn0 + wc * 64 + j * 16 + lr;
    const float bv = bias[col];
    const float sc = (QKV_SCALE && col < DIMC) ? SCALE : 1.0f;
#pragma unroll
    for (int i = 0; i < 4; ++i) {
      const int row0 = bm0 + wr * 64 + i * 16 + lg * 4;
#pragma unroll
      for (int r = 0; r < 4; ++r) {
        const float val = (acc[i][j][r] + bv) * sc;
        if (OUT_BF16)
          ((u16*)Cp)[(size_t)(row0 + r) * N + col] = f2bf(val);
        else
          ((float*)Cp)[(size_t)(row0 + r) * N + col] = val;
      }
    }
  }
}

// ---------------- fused window attention ----------------
// 1 wave per (window, head). qkv: [B_*49][1536] bf16 (q scaled already).
// biasmask: [64*16][64*64] fp32 (pad -1e30). out: [B_*49][512] bf16.
__global__ void attn_win(const u16* __restrict__ qkv, const float* __restrict__ bmask,
                         u16* __restrict__ aout) {
  __shared__ u16 P[4][64 * 72];   // per-wave P tile, stride 72 (pad)
  const int t = threadIdx.x, lane = t & 63, wv = t >> 6;
  const int lr = lane & 15, lg = lane >> 4;
  const int w = blockIdx.x >> 2;
  const int h = ((blockIdx.x & 3) << 2) + wv;
  const size_t base = (size_t)w * NTOK * 1536 + h * HEAD_DIM;

  const bf16x8 zf = {};
  bf16x8 qf[4], kf[4];
#pragma unroll
  for (int i = 0; i < 4; ++i) {
    const int row = i * 16 + lr;
    const size_t roff = base + (size_t)row * 1536 + lg * 8;
    qf[i] = (row < NTOK) ? *(const bf16x8*)&qkv[roff] : zf;          // Q(row, d..)
    kf[i] = (row < NTOK) ? *(const bf16x8*)&qkv[roff + DIMC] : zf;   // K(row, d..)
  }

  const f32x4 zc = {};
  f32x4 s[4][4];
#pragma unroll
  for (int i = 0; i < 4; ++i)
#pragma unroll
    for (int j = 0; j < 4; ++j)
      s[i][j] = MFMA16(qf[i], kf[j], zc);   // S = (Q*scale) K^T

  const float* bmp = bmask + (((size_t)(w & 63) * HEADS + h) << 12);
#pragma unroll
  for (int i = 0; i < 4; ++i)
#pragma unroll
    for (int r = 0; r < 4; ++r) {
      const int ii = i * 16 + lg * 4 + r;
#pragma unroll
      for (int j = 0; j < 4; ++j)
        s[i][j][r] += bmp[ii * 64 + j * 16 + lr];
    }

  // softmax over each row: 4 in-lane values x 16 lanes (shfl_xor 1,2,4,8)
#pragma unroll
  for (int i = 0; i < 4; ++i)
#pragma unroll
    for (int r = 0; r < 4; ++r) {
      float m = fmaxf(fmaxf(s[i][0][r], s[i][1][r]), fmaxf(s[i][2][r], s[i][3][r]));
      m = fmaxf(m, __shfl_xor(m, 1));
      m = fmaxf(m, __shfl_xor(m, 2));
      m = fmaxf(m, __shfl_xor(m, 4));
      m = fmaxf(m, __shfl_xor(m, 8));
      float sum = 0.f;
#pragma unroll
      for (int j = 0; j < 4; ++j) {
        const float e = __expf(s[i][j][r] - m);
        s[i][j][r] = e;
        sum += e;
      }
      sum += __shfl_xor(sum, 1);
      sum += __shfl_xor(sum, 2);
      sum += __shfl_xor(sum, 4);
      sum += __shfl_xor(sum, 8);
      const float rinv = __builtin_amdgcn_rcpf(sum);
#pragma unroll
      for (int j = 0; j < 4; ++j) s[i][j][r] *= rinv;
    }

  // P -> LDS (bf16), C/D layout scatter
  u16* Pw = &P[wv][0];
#pragma unroll
  for (int i = 0; i < 4; ++i)
#pragma unroll
    for (int r = 0; r < 4; ++r) {
      const int ii = i * 16 + lg * 4 + r;
#pragma unroll
      for (int j = 0; j < 4; ++j)
        Pw[ii * 72 + j * 16 + lr] = f2bf(s[i][j][r]);
    }

  // PV: out[i][d] = sum_k P[i][k] V[k][d]; K=64 (2 steps), pad keys have P==0
  f32x4 o[4][2] = {};
#pragma unroll
  for (int ks = 0; ks < 2; ++ks) {
    bf16x8 vf[2];
#pragma unroll
    for (int dn = 0; dn < 2; ++dn) {
#pragma unroll
      for (int e = 0; e < 8; ++e) {
        int kk = ks * 32 + lg * 8 + e;
        kk = kk < NTOK ? kk : 0;   // P is exactly 0 for padded keys
        vf[dn][e] = (short)qkv[base + 2 * DIMC + (size_t)kk * 1536 + dn * 16 + lr];
      }
    }
#pragma unroll
    for (int i = 0; i < 4; ++i) {
      const bf16x8 pa = *(const bf16x8*)&Pw[(i * 16 + lr) * 72 + ks * 32 + lg * 8];
#pragma unroll
      for (int dn = 0; dn < 2; ++dn)
        o[i][dn] = MFMA16(pa, vf[dn], o[i][dn]);
    }
  }

  // store attention output -> [token][h*32+d] bf16
#pragma unroll
  for (int i = 0; i < 4; ++i)
#pragma unroll
    for (int r = 0; r < 4; ++r) {
      const int row = i * 16 + lg * 4 + r;
      if (row < NTOK) {
        const size_t ob = ((size_t)w * NTOK + row) * DIMC + h * HEAD_DIM;
#pragma unroll
        for (int dn = 0; dn < 2; ++dn)
          aout[ob + dn * 16 + lr] = f2bf(o[i][dn][r]);
      }
    }
}

// ---------------- launch ----------------
extern "C" void kernel_launch(void* const* d_in, const int* in_sizes, int n_in,
                              void* d_out, int out_size, void* d_ws, size_t ws_size,
                              hipStream_t stream) {
  const float* x      = (const float*)d_in[0];   // (4096,49,512)
  const float* mask   = (const float*)d_in[1];   // (64,49,49)
  const float* qkv_w  = (const float*)d_in[2];   // (1536,512)
  const float* qkv_b  = (const float*)d_in[3];   // (1536,)
  const float* table  = (const float*)d_in[4];   // (169,16)
  const float* proj_w = (const float*)d_in[5];   // (512,512)
  const float* proj_b = (const float*)d_in[6];   // (512,)
  float* out = (float*)d_out;

  const int M = 4096 * NTOK;   // 200704

  char* ws = (char*)d_ws;
  u16*   qkv_bf   = (u16*)ws;                         // 200704*1536*2 = 616,562,688
  u16*   wqkv_bf  = (u16*)(ws + 616562688ull);        // 1536*512*2    = 1,572,864
  u16*   wproj_bf = (u16*)(ws + 618135552ull);        // 512*512*2     = 524,288
  float* biasmask = (float*)(ws + 618659840ull);      // 1024*4096*4   = 16,777,216
  // x_bf and attn_bf SHARE this region (disjoint lifetimes, same size):
  // x_bf live: cvt -> gemm1.  attn_bf live: attn_win -> gemm2.
  u16*   x_bf     = (u16*)(ws + 635437056ull);        // 200704*512*2  = 205,520,896
  u16*   attn_bf  = x_bf;
  // total 840,957,952 bytes

  cvt_f32_bf16<<<768, 256, 0, stream>>>(qkv_w, wqkv_bf, 1536 * 512);
  cvt_f32_bf16<<<256, 256, 0, stream>>>(proj_w, wproj_bf, 512 * 512);
  biasmask_kernel<<<1024, 256, 0, stream>>>(table, mask, biasmask);
  cvt_f32_bf16<<<1792, 256, 0, stream>>>(x, x_bf, M * DIMC);   // 1792*256*8*28 == M*DIMC

  // QKV GEMM: (M,1536,512); grid 1568*12 = 18816 (%8==0)
  gemm_bf16<true, true><<<1568 * 12, 256, 0, stream>>>(
      x_bf, wqkv_bf, qkv_b, qkv_bf, M, 1536, 512, 12);

  attn_win<<<4096 * 4, 256, 0, stream>>>(qkv_bf, biasmask, attn_bf);

  // proj GEMM: (M,512,512); grid 1568*4 = 6272 (%8==0)
  gemm_bf16<false, false><<<1568 * 4, 256, 0, stream>>>(
      attn_bf, wproj_bf, proj_b, out, M, 512, 512, 4);
}